// Round 1
// baseline (993.520 us; speedup 1.0000x reference)
//
#include <hip/hip_runtime.h>

typedef unsigned int u32;
typedef unsigned short u16;
typedef __fp16 h2 __attribute__((ext_vector_type(2)));

#define BB 16
#define LL 2048
#define DD 64
#define RPB 8            // rows per block (4 waves; pass1: 2 rows/wave)
#define NTHREADS 256

union U32H2 { u32 u; h2 h; };
__device__ __forceinline__ h2  as_h2(u32 x) { U32H2 t; t.u = x; return t.h; }
__device__ __forceinline__ u32 as_u32(h2 x) { U32H2 t; t.h = x; return t.u; }

__device__ __forceinline__ h2 pk(float x, float y) {
#if __has_builtin(__builtin_amdgcn_cvt_pkrtz)
    return __builtin_amdgcn_cvt_pkrtz(x, y);
#else
    h2 r; r.x = (__fp16)x; r.y = (__fp16)y; return r;
#endif
}

__device__ __forceinline__ float fdot2f(u32 a, u32 b, float c) {
#if __has_builtin(__builtin_amdgcn_fdot2)
    return __builtin_amdgcn_fdot2(as_h2(a), as_h2(b), c, false);
#else
    h2 ha = as_h2(a), hb = as_h2(b);
    c = fmaf((float)ha.x, (float)hb.x, c);
    return fmaf((float)ha.y, (float)hb.y, c);
#endif
}

// S[b,r,c] = (q[r]·k[c] + q[r]·e[c + 2047 - r]) / 8 for c <= r; softmax; O = P@V.
__global__ __launch_bounds__(NTHREADS, 3) void attn_fused(
    const float* __restrict__ qg, const float* __restrict__ kg,
    const float* __restrict__ vg, const float* __restrict__ eg,
    float* __restrict__ out_o, float* __restrict__ out_attn)
{
    // XOR-swizzled fp16-pair tiles: element (row, pair p) at [row][p ^ ((row&7)<<2)]
    __shared__ u32 k_sw[64][32];        // 8 KB  (also reused as O-reduction scratch)
    __shared__ u32 e_sw[72][32];        // 9 KB
    __shared__ __fp16 S_h[RPB][LL];     // 32 KB: scores then probabilities
    __shared__ u32 q_su[RPB][32];       // packed q rows
    __shared__ float linv[RPB];

    const int tid  = threadIdx.x;
    const int wave = tid >> 6;
    const int lane = tid & 63;
    const int b    = blockIdx.x / (LL / RPB);
    // LPT: reverse row-block order so heaviest causal blocks dispatch first
    const int r0   = ((LL / RPB) - 1 - (blockIdx.x % (LL / RPB))) * RPB;

    const float* kb  = kg + (size_t)b * LL * DD;
    const float* ebs = eg + (size_t)b * LL * DD;
    const float* vb  = vg + (size_t)b * LL * DD;

    // ---- stage q (packed fp16 pairs) ----
    {
        int r = tid >> 5, p = tid & 31;
        float2 qv = *(const float2*)(qg + ((size_t)b * LL + r0 + r) * DD + 2 * p);
        q_su[r][p] = as_u32(pk(qv.x, qv.y));
    }
    __syncthreads();

    const int ia = wave * 2, ib = ia + 1;
    const int ra = r0 + ia, rb = r0 + ib;
    const int nT = (r0 >> 6) + 1;       // block rows never straddle a 64-tile

    u32 qa_h[32], qb_h[32];
#pragma unroll
    for (int p = 0; p < 32; ++p) { qa_h[p] = q_su[ia][p]; qb_h[p] = q_su[ib][p]; }

    float ma = -1e30f, mb = -1e30f;

    // prefetch registers for the k/e tile staging (T14 async-stage split)
    float2 kpre[8];
    float2 epre[9];

#define ISSUE_TILE(T) do {                                                     \
        const int c0_ = (T) << 6;                                              \
        _Pragma("unroll")                                                      \
        for (int j = 0; j < 8; ++j) {                                          \
            int idx = tid + j * 256; int r = idx >> 5, p = idx & 31;           \
            kpre[j] = *(const float2*)(kb + (size_t)(c0_ + r) * DD + 2 * p);   \
        }                                                                      \
        const int elo_ = c0_ + (LL - RPB) - r0;                                \
        _Pragma("unroll")                                                      \
        for (int j = 0; j < 9; ++j) {                                          \
            int idx = tid + j * 256; int r = idx >> 5, p = idx & 31;           \
            int gr = elo_ + r; if (gr > LL - 1) gr = LL - 1;                   \
            epre[j] = *(const float2*)(ebs + (size_t)gr * DD + 2 * p);         \
        }                                                                      \
    } while (0)

    ISSUE_TILE(0);

    // ================= pass 1: scores =================
    for (int t = 0; t < nT; ++t) {
        __syncthreads();                 // protect LDS tiles from prior readers
        // drain prefetched tile into LDS (swizzled)
#pragma unroll
        for (int j = 0; j < 8; ++j) {
            int idx = tid + j * 256;
            int r = idx >> 5, p = idx & 31;
            k_sw[r][p ^ ((r & 7) << 2)] = as_u32(pk(kpre[j].x, kpre[j].y));
        }
#pragma unroll
        for (int j = 0; j < 9; ++j) {
            int idx = tid + j * 256;
            int r = idx >> 5, p = idx & 31;
            e_sw[r][p ^ ((r & 7) << 2)] = as_u32(pk(epre[j].x, epre[j].y));
        }
        if (t + 1 < nT) ISSUE_TILE(t + 1);   // latency hides under compute below
        __syncthreads();

        const int c0 = t << 6;
        const int c = c0 + lane;
        const int reA = lane + 7 - 2 * wave;     // local e row for row ra
        const int reB = reA - 1;                 // for row rb
        const u32* kr = k_sw[lane];
        const u32* ar = e_sw[reA];
        const u32* br = e_sw[reB];
        const int sk = (lane & 7) << 2, sa = (reA & 7) << 2, sb = (reB & 7) << 2;
        float dka = 0.f, dkb = 0.f, dea = 0.f, deb = 0.f;
#pragma unroll
        for (int t4 = 0; t4 < 8; ++t4) {
            uint4 kq = *(const uint4*)&kr[(4 * t4) ^ sk];
            uint4 aq = *(const uint4*)&ar[(4 * t4) ^ sa];
            uint4 bq = *(const uint4*)&br[(4 * t4) ^ sb];
            dka = fdot2f(qa_h[4*t4+0], kq.x, dka);
            dka = fdot2f(qa_h[4*t4+1], kq.y, dka);
            dka = fdot2f(qa_h[4*t4+2], kq.z, dka);
            dka = fdot2f(qa_h[4*t4+3], kq.w, dka);
            dkb = fdot2f(qb_h[4*t4+0], kq.x, dkb);
            dkb = fdot2f(qb_h[4*t4+1], kq.y, dkb);
            dkb = fdot2f(qb_h[4*t4+2], kq.z, dkb);
            dkb = fdot2f(qb_h[4*t4+3], kq.w, dkb);
            dea = fdot2f(qa_h[4*t4+0], aq.x, dea);
            dea = fdot2f(qa_h[4*t4+1], aq.y, dea);
            dea = fdot2f(qa_h[4*t4+2], aq.z, dea);
            dea = fdot2f(qa_h[4*t4+3], aq.w, dea);
            deb = fdot2f(qb_h[4*t4+0], bq.x, deb);
            deb = fdot2f(qb_h[4*t4+1], bq.y, deb);
            deb = fdot2f(qb_h[4*t4+2], bq.z, deb);
            deb = fdot2f(qb_h[4*t4+3], bq.w, deb);
        }
        float Sa = (dka + dea) * 0.125f;
        float Sb = (dkb + deb) * 0.125f;
        if (c > ra) Sa = -60000.0f;      // fp16-safe "-inf"
        if (c > rb) Sb = -60000.0f;
        ma = fmaxf(ma, Sa);
        mb = fmaxf(mb, Sb);
        S_h[ia][c] = (__fp16)Sa;
        S_h[ib][c] = (__fp16)Sb;
    }

#pragma unroll
    for (int off = 32; off; off >>= 1) {
        ma = fmaxf(ma, __shfl_xor(ma, off, 64));
        mb = fmaxf(mb, __shfl_xor(mb, off, 64));
    }

    // ================= pass 2: exp + sum =================
    float la = 0.f, lb = 0.f;
    for (int t = 0; t < nT; ++t) {
        const int c = (t << 6) + lane;
        float pa = __expf((float)S_h[ia][c] - ma);   // masked -> 0
        float pb = __expf((float)S_h[ib][c] - mb);
        la += pa; lb += pb;
        S_h[ia][c] = (__fp16)pa;
        S_h[ib][c] = (__fp16)pb;
    }
#pragma unroll
    for (int off = 32; off; off >>= 1) {
        la += __shfl_xor(la, off, 64);
        lb += __shfl_xor(lb, off, 64);
    }
    const float inva = 1.f / la, invb = 1.f / lb;
    if (lane == 0) { linv[ia] = inva; linv[ib] = invb; }

    // ================= pass 3: attn store (fp32) =================
    float* arow_a = out_attn + ((size_t)b * LL + ra) * LL;
    float* arow_b = out_attn + ((size_t)b * LL + rb) * LL;
#pragma unroll 4
    for (int t = 0; t < LL / 64; ++t) {
        const int c = (t << 6) + lane;
        float pa = (c <= ra) ? (float)S_h[ia][c] * inva : 0.f;
        float pb = (c <= rb) ? (float)S_h[ib][c] * invb : 0.f;
        arow_a[c] = pa;
        arow_b[c] = pb;
    }

    __syncthreads();   // all pass-1 LDS reads done; S_h fully holds p

    // ================= pass 4: O = P@V, wave-strided tiles, 2-deep V pipeline =================
    float o[8] = {0.f, 0.f, 0.f, 0.f, 0.f, 0.f, 0.f, 0.f};

#define LOADV(dst, CH) {                                                       \
        const float* vp_ = vb + (size_t)(tb + ((CH) << 3)) * DD + lane;        \
        _Pragma("unroll")                                                      \
        for (int j = 0; j < 8; ++j) (dst)[j] = vp_[j * DD]; }

#define PVCHUNK(src, CH) {                                                     \
        u32 vv0 = as_u32(pk((src)[0], (src)[1]));                              \
        u32 vv1 = as_u32(pk((src)[2], (src)[3]));                              \
        u32 vv2 = as_u32(pk((src)[4], (src)[5]));                              \
        u32 vv3 = as_u32(pk((src)[6], (src)[7]));                              \
        const int cb = tb + ((CH) << 3);                                       \
        _Pragma("unroll")                                                      \
        for (int ri = 0; ri < 8; ++ri) {                                       \
            uint4 pq = *(const uint4*)&S_h[ri][cb];   /* broadcast b128 */     \
            o[ri] = fdot2f(pq.x, vv0, o[ri]);                                  \
            o[ri] = fdot2f(pq.y, vv1, o[ri]);                                  \
            o[ri] = fdot2f(pq.z, vv2, o[ri]);                                  \
            o[ri] = fdot2f(pq.w, vv3, o[ri]);                                  \
        } }

    for (int t = wave; t < nT; t += 4) {
        const int tb = t << 6;
        float vA[8], vB[8];
        LOADV(vA, 0)
        LOADV(vB, 1)
        PVCHUNK(vA, 0)
        LOADV(vA, 2)
        PVCHUNK(vB, 1)
        LOADV(vB, 3)
        PVCHUNK(vA, 2)
        LOADV(vA, 4)
        PVCHUNK(vB, 3)
        LOADV(vB, 5)
        PVCHUNK(vA, 4)
        LOADV(vA, 6)
        PVCHUNK(vB, 5)
        LOADV(vB, 7)
        PVCHUNK(vA, 6)
        PVCHUNK(vB, 7)
    }

    float* ored = (float*)k_sw;          // reuse 8 KB: [4 waves][8 rows][64]
#pragma unroll
    for (int ri = 0; ri < 8; ++ri) ored[(wave * 8 + ri) * 64 + lane] = o[ri];
    __syncthreads();

#pragma unroll
    for (int j = 0; j < 2; ++j) {
        int i = tid + j * 256;           // 0..511
        int ri = i >> 6, d = i & 63;
        float s = ored[(0 * 8 + ri) * 64 + d] + ored[(1 * 8 + ri) * 64 + d]
                + ored[(2 * 8 + ri) * 64 + d] + ored[(3 * 8 + ri) * 64 + d];
        out_o[((size_t)b * LL + r0 + ri) * DD + d] = s * linv[ri];
    }
}

extern "C" void kernel_launch(void* const* d_in, const int* in_sizes, int n_in,
                              void* d_out, int out_size, void* d_ws, size_t ws_size,
                              hipStream_t stream) {
    const float* q = (const float*)d_in[0];
    const float* k = (const float*)d_in[1];
    const float* v = (const float*)d_in[2];
    const float* e = (const float*)d_in[3];
    // d_in[4] = mask: causal, deterministic -> unused
    float* out_o    = (float*)d_out;
    float* out_attn = out_o + (size_t)BB * LL * DD;

    dim3 grid(BB * (LL / RPB));
    attn_fused<<<grid, NTHREADS, 0, stream>>>(q, k, v, e, out_o, out_attn);
}

// Round 2
// 780.086 us; speedup vs baseline: 1.2736x; 1.2736x over previous
//
#include <hip/hip_runtime.h>

typedef unsigned int u32;
typedef __fp16 h2 __attribute__((ext_vector_type(2)));
typedef _Float16 f16x8 __attribute__((ext_vector_type(8)));
typedef float f32x4 __attribute__((ext_vector_type(4)));

#define BB 16
#define LL 2048
#define DD 64
#define RPB 16           // rows per block (MFMA granularity)
#define NTHREADS 256
#define NBLK (LL / RPB)  // 128 row-blocks per batch

union U32H2 { u32 u; h2 h; };
__device__ __forceinline__ u32 as_u32(h2 x) { U32H2 t; t.h = x; return t.u; }

__device__ __forceinline__ h2 pk(float x, float y) {
#if __has_builtin(__builtin_amdgcn_cvt_pkrtz)
    return __builtin_amdgcn_cvt_pkrtz(x, y);
#else
    h2 r; r.x = (__fp16)x; r.y = (__fp16)y; return r;
#endif
}

__device__ __forceinline__ float fdot2f(u32 a, u32 b, float c) {
#if __has_builtin(__builtin_amdgcn_fdot2)
    U32H2 ta; ta.u = a; U32H2 tb; tb.u = b;
    return __builtin_amdgcn_fdot2(ta.h, tb.h, c, false);
#else
    U32H2 ta; ta.u = a; U32H2 tb; tb.u = b;
    c = fmaf((float)ta.h.x, (float)tb.h.x, c);
    return fmaf((float)ta.h.y, (float)tb.h.y, c);
#endif
}

union F8U { f16x8 v; h2 p[4]; };
__device__ __forceinline__ f16x8 pack8(float4 a, float4 b) {
    F8U u;
    u.p[0] = pk(a.x, a.y); u.p[1] = pk(a.z, a.w);
    u.p[2] = pk(b.x, b.y); u.p[3] = pk(b.z, b.w);
    return u.v;
}

#define MFMA(A, B, C) __builtin_amdgcn_mfma_f32_16x16x32_f16((A), (B), (C), 0, 0, 0)

// S[b,r,c] = (q[r]·k[c] + q[r]·e[c + 2047 - r]) / 8 for c <= r; softmax; O = P@V.
// MFMA fragment conventions (16x16x32 f16):
//   A: lane holds row = lane&15, k = 8*(lane>>4)+e (e=0..7)
//   B: lane holds col = lane&15, k = 8*(lane>>4)+e
//   C/D: lane holds col = lane&15, row = (lane>>4)*4 + reg   [m89-verified]
__global__ __launch_bounds__(NTHREADS, 2) void attn_fused(
    const float* __restrict__ qg, const float* __restrict__ kg,
    const float* __restrict__ vg, const float* __restrict__ eg,
    float* __restrict__ out_o, float* __restrict__ out_attn)
{
    __shared__ __fp16 S_h[RPB][LL];        // 64 KB: scores -> probabilities; reused as O-reduction
    __shared__ float  G_scr[4][RPB][34];   // 8.5 KB: per-wave G strip (stride 34 kills conflicts)
    __shared__ float  maxbuf[RPB][64];     // 4 KB: per-lane running maxes
    __shared__ float  linv[RPB];

    const int tid  = threadIdx.x;
    const int wave = tid >> 6;
    const int lane = tid & 63;
    const int o4   = lane >> 4;            // k-octet group
    const int lc   = lane & 15;            // row (A) / col (B) index
    const int b    = blockIdx.x / NBLK;
    const int r0   = (blockIdx.x % NBLK) * RPB;
    const int nT   = (r0 >> 6) + 1;        // 64-col sweep steps (block rows never straddle)

    const float* qb = qg + (size_t)b * LL * DD;
    const float* kb = kg + (size_t)b * LL * DD;
    const float* eb = eg + (size_t)b * LL * DD;
    const float* vb = vg + (size_t)b * LL * DD;

    // ---- Q A-fragments (held in registers for whole pass 1) ----
    f16x8 qa0, qa1;
    {
        const float* qr = qb + (size_t)(r0 + lc) * DD + 8 * o4;
        float4 a0 = *(const float4*)(qr);
        float4 a1 = *(const float4*)(qr + 4);
        float4 b0 = *(const float4*)(qr + 32);
        float4 b1 = *(const float4*)(qr + 36);
        qa0 = pack8(a0, a1);               // k = 0..31 octet
        qa1 = pack8(b0, b1);               // k = 32..63 octet
    }

    float mx[4] = {-60000.f, -60000.f, -60000.f, -60000.f};
    float* Gp = &G_scr[wave][0][0];

    // wave w computes col-subtile [64t+16w, +16); it has live (unmasked) work while
    // 64t + 16w <= r0 + 15
    const int span = r0 + 15 - (wave << 4);
    const int nTw  = (span >= 0) ? ((span >> 6) + 1) : 0;

    // ================= pass 1: scores via MFMA (barrier-free, waves independent) ==========
    for (int t = 0; t < nTw; ++t) {
        const int c0w = (t << 6) + (wave << 4);

        // K B-frags: lane -> key row c0w+lc, d-octet 8*o4 (+32 for kstep1)
        const float* kr = kb + (size_t)(c0w + lc) * DD + 8 * o4;
        float4 k0 = *(const float4*)(kr);
        float4 k1 = *(const float4*)(kr + 4);
        float4 k2 = *(const float4*)(kr + 32);
        float4 k3 = *(const float4*)(kr + 36);

        // E B-frags: G[rl][lj] = q[r0+rl] . e[j0w + lj],  j0w = c0w + 2032 - r0
        const int j0w = c0w + 2032 - r0;   // >= 0 always
        int er0 = j0w + lc;      if (er0 > LL - 1) er0 = LL - 1;  // clamp hits masked-only
        int er1 = j0w + 16 + lc; if (er1 > LL - 1) er1 = LL - 1;
        const float* e0p = eb + (size_t)er0 * DD + 8 * o4;
        const float* e1p = eb + (size_t)er1 * DD + 8 * o4;
        float4 ea0 = *(const float4*)(e0p);
        float4 ea1 = *(const float4*)(e0p + 4);
        float4 ea2 = *(const float4*)(e0p + 32);
        float4 ea3 = *(const float4*)(e0p + 36);
        float4 eb0 = *(const float4*)(e1p);
        float4 eb1 = *(const float4*)(e1p + 4);
        float4 eb2 = *(const float4*)(e1p + 32);
        float4 eb3 = *(const float4*)(e1p + 36);

        f16x8 kf0 = pack8(k0, k1), kf1 = pack8(k2, k3);
        f16x8 ef00 = pack8(ea0, ea1), ef01 = pack8(ea2, ea3);
        f16x8 ef10 = pack8(eb0, eb1), ef11 = pack8(eb2, eb3);

        const f32x4 z = {0.f, 0.f, 0.f, 0.f};
        f32x4 dk = MFMA(qa0, kf0, z);  dk = MFMA(qa1, kf1, dk);
        f32x4 g0 = MFMA(qa0, ef00, z); g0 = MFMA(qa1, ef01, g0);
        f32x4 g1 = MFMA(qa0, ef10, z); g1 = MFMA(qa1, ef11, g1);

        // spill G strip to per-wave scratch (wave-private; same-wave DS ops are in-order)
#pragma unroll
        for (int i = 0; i < 4; ++i) {
            Gp[(4 * o4 + i) * 34 + lc]      = g0[i];
            Gp[(4 * o4 + i) * 34 + 16 + lc] = g1[i];
        }
        // sheared read + combine + mask + store S
#pragma unroll
        for (int i = 0; i < 4; ++i) {
            const int rl = 4 * o4 + i;
            const int lj = lc - rl + 15;         // in [0,30]
            float s = (dk[i] + Gp[rl * 34 + lj]) * 0.125f;
            const int c = c0w + lc;
            if (c > r0 + rl) s = -60000.f;       // fp16-safe "-inf"
            mx[i] = fmaxf(mx[i], s);
            S_h[rl][c] = (__fp16)s;
        }
    }

#pragma unroll
    for (int i = 0; i < 4; ++i)
        maxbuf[4 * o4 + i][(wave << 4) + lc] = mx[i];
    __syncthreads();

    // ================= pass 2+3: softmax + attn store (wave w owns rows 4w..4w+3) =========
    for (int ri2 = 0; ri2 < 4; ++ri2) {
        const int rl = (wave << 2) + ri2;
        const int r  = r0 + rl;
        float m = maxbuf[rl][lane];
#pragma unroll
        for (int off = 32; off; off >>= 1) m = fmaxf(m, __shfl_xor(m, off, 64));
        float l = 0.f;
        for (int t = 0; t < nT; ++t) {
            const int c = (t << 6) + lane;
            float p = (c <= r) ? __expf((float)S_h[rl][c] - m) : 0.f;
            l += p;
            S_h[rl][c] = (__fp16)p;
        }
#pragma unroll
        for (int off = 32; off; off >>= 1) l += __shfl_xor(l, off, 64);
        const float inv = 1.f / l;
        if (lane == 0) linv[rl] = inv;
        float* arow = out_attn + ((size_t)b * LL + r) * LL;
#pragma unroll 4
        for (int t = 0; t < LL / 64; ++t) {
            const int c = (t << 6) + lane;
            arow[c] = (c <= r) ? (float)S_h[rl][c] * inv : 0.f;
        }
    }
    __syncthreads();   // all P values in S_h, all rows

    // ================= pass 4: O = P@V, wave-strided key tiles, all 16 rows ===============
    float o[16];
#pragma unroll
    for (int i = 0; i < 16; ++i) o[i] = 0.f;

    for (int t = wave; t < nT; t += 4) {
#pragma unroll
        for (int ch = 0; ch < 8; ++ch) {
            const int cb = (t << 6) + (ch << 3);
            const float* vp = vb + (size_t)cb * DD + lane;
            float v0 = vp[0],      v1 = vp[DD],     v2 = vp[2*DD], v3 = vp[3*DD];
            float v4 = vp[4*DD],   v5 = vp[5*DD],   v6 = vp[6*DD], v7 = vp[7*DD];
            u32 vv0 = as_u32(pk(v0, v1)), vv1 = as_u32(pk(v2, v3));
            u32 vv2 = as_u32(pk(v4, v5)), vv3 = as_u32(pk(v6, v7));
#pragma unroll
            for (int ri = 0; ri < 16; ++ri) {
                uint4 pq = *(const uint4*)&S_h[ri][cb];   // broadcast b128
                o[ri] = fdot2f(pq.x, vv0, o[ri]);
                o[ri] = fdot2f(pq.y, vv1, o[ri]);
                o[ri] = fdot2f(pq.z, vv2, o[ri]);
                o[ri] = fdot2f(pq.w, vv3, o[ri]);
            }
        }
    }
    __syncthreads();   // all S_h reads done -> safe to reuse as reduction scratch

    float* ored = (float*)S_h;             // [4 waves][16 rows][64]
#pragma unroll
    for (int ri = 0; ri < 16; ++ri) ored[(wave * 16 + ri) * 64 + lane] = o[ri];
    __syncthreads();

#pragma unroll
    for (int j = 0; j < 4; ++j) {
        const int i  = tid + j * 256;      // 0..1023
        const int ri = i >> 6, d = i & 63;
        float s = ored[(0 * 16 + ri) * 64 + d] + ored[(1 * 16 + ri) * 64 + d]
                + ored[(2 * 16 + ri) * 64 + d] + ored[(3 * 16 + ri) * 64 + d];
        out_o[((size_t)b * LL + r0 + ri) * DD + d] = s * linv[ri];
    }
}

extern "C" void kernel_launch(void* const* d_in, const int* in_sizes, int n_in,
                              void* d_out, int out_size, void* d_ws, size_t ws_size,
                              hipStream_t stream) {
    const float* q = (const float*)d_in[0];
    const float* k = (const float*)d_in[1];
    const float* v = (const float*)d_in[2];
    const float* e = (const float*)d_in[3];
    // d_in[4] = mask: causal, deterministic -> unused
    float* out_o    = (float*)d_out;
    float* out_attn = out_o + (size_t)BB * LL * DD;

    dim3 grid(BB * NBLK);
    attn_fused<<<grid, NTHREADS, 0, stream>>>(q, k, v, e, out_o, out_attn);
}

// Round 3
// 651.614 us; speedup vs baseline: 1.5247x; 1.1972x over previous
//
#include <hip/hip_runtime.h>

typedef unsigned int u32;
typedef __fp16 h2 __attribute__((ext_vector_type(2)));
typedef _Float16 f16x8 __attribute__((ext_vector_type(8)));
typedef float f32x4 __attribute__((ext_vector_type(4)));

#define BB 16
#define LL 2048
#define DD 64
#define RPB 16           // rows per block (MFMA granularity)
#define NTHREADS 512     // 8 waves
#define NBLK (LL / RPB)  // 128 row-blocks per batch

__device__ __forceinline__ h2 pk(float x, float y) {
#if __has_builtin(__builtin_amdgcn_cvt_pkrtz)
    return __builtin_amdgcn_cvt_pkrtz(x, y);
#else
    h2 r; r.x = (__fp16)x; r.y = (__fp16)y; return r;
#endif
}

union F8U { f16x8 v; h2 p[4]; };
__device__ __forceinline__ f16x8 pack8(float4 a, float4 b) {
    F8U u;
    u.p[0] = pk(a.x, a.y); u.p[1] = pk(a.z, a.w);
    u.p[2] = pk(b.x, b.y); u.p[3] = pk(b.z, b.w);
    return u.v;
}

#define MFMA(A, B, C) __builtin_amdgcn_mfma_f32_16x16x32_f16((A), (B), (C), 0, 0, 0)

// S_h column swizzle (fp16-unit index within a row): keeps 16B granules intact,
// spreads rows 0..7 across granule slots -> conflict-free b128 column reads.
__device__ __forceinline__ int swc(int rl, int c) { return c ^ ((rl & 7) << 3); }

// S[b,r,c] = (q[r]·k[c] + q[r]·e[c + 2047 - r]) / 8 for c <= r; softmax; O = P@V.
// MFMA fragment conventions (16x16x32 f16), verified on-chip in prior round:
//   A: lane holds row = lane&15, k = 8*(lane>>4)+e (e=0..7, contiguous)
//   B: lane holds col = lane&15, k = 8*(lane>>4)+e
//   C/D: lane holds col = lane&15, row = 4*(lane>>4) + reg
__global__ __launch_bounds__(NTHREADS, 4) void attn_fused(
    const float* __restrict__ qg, const float* __restrict__ kg,
    const float* __restrict__ vg, const float* __restrict__ eg,
    float* __restrict__ out_o, float* __restrict__ out_attn)
{
    __shared__ __fp16 S_h[RPB][LL];      // 64 KB: scores -> probabilities (swizzled cols)
    __shared__ float  maxF[RPB][132];    // 8.25 KB: per-subtile max partials; reused as O-red scratch
    __shared__ float  linv[RPB];

    const int tid  = threadIdx.x;
    const int wave = tid >> 6;           // 0..7
    const int lane = tid & 63;
    const int o4   = lane >> 4;          // k-octet group 0..3
    const int lc   = lane & 15;          // row (A) / col (B) index
    const int b    = blockIdx.x / NBLK;
    const int r0   = (blockIdx.x % NBLK) * RPB;
    const int nT   = (r0 >> 6) + 1;      // 64-col steps covering causal span

    const float* qb = qg + (size_t)b * LL * DD;
    const float* kb = kg + (size_t)b * LL * DD;
    const float* eb = eg + (size_t)b * LL * DD;
    const float* vb = vg + (size_t)b * LL * DD;

    // ---- Q A-fragments (registers for whole pass 1) ----
    f16x8 qa0, qa1;
    {
        const float* qr = qb + (size_t)(r0 + lc) * DD + 8 * o4;
        float4 a0 = *(const float4*)(qr);
        float4 a1 = *(const float4*)(qr + 4);
        float4 b0 = *(const float4*)(qr + 32);
        float4 b1 = *(const float4*)(qr + 36);
        qa0 = pack8(a0, a1);             // k = 0..31 octet
        qa1 = pack8(b0, b1);             // k = 32..63 octet
    }

    float mx[4] = {-60000.f, -60000.f, -60000.f, -60000.f};

    // wave w owns 16-col subtile at 128t + 16w; live while col-base <= r0+15
    const int span = r0 + 15 - (wave << 4);
    const int nTw  = (span >= 0) ? ((span >> 7) + 1) : 0;

    // ================= pass 1: scores via MFMA (barrier-free) =================
    for (int t = 0; t < nTw; ++t) {
        const int c0w = (t << 7) + (wave << 4);

        // K B-frags
        const float* kr = kb + (size_t)(c0w + lc) * DD + 8 * o4;
        float4 k0 = *(const float4*)(kr);
        float4 k1 = *(const float4*)(kr + 4);
        float4 k2 = *(const float4*)(kr + 32);
        float4 k3 = *(const float4*)(kr + 36);

        // E B-frags: G[rl][lj] = q[r0+rl] . e[j0w + lj]
        const int j0w = c0w + 2032 - r0;            // >= 0 always
        int er0 = j0w + lc;      if (er0 > LL - 1) er0 = LL - 1;  // clamp: masked-only
        int er1 = j0w + 16 + lc; if (er1 > LL - 1) er1 = LL - 1;
        const float* e0p = eb + (size_t)er0 * DD + 8 * o4;
        const float* e1p = eb + (size_t)er1 * DD + 8 * o4;
        float4 ea0 = *(const float4*)(e0p);
        float4 ea1 = *(const float4*)(e0p + 4);
        float4 ea2 = *(const float4*)(e0p + 32);
        float4 ea3 = *(const float4*)(e0p + 36);
        float4 eb0 = *(const float4*)(e1p);
        float4 eb1 = *(const float4*)(e1p + 4);
        float4 eb2 = *(const float4*)(e1p + 32);
        float4 eb3 = *(const float4*)(e1p + 36);

        f16x8 kf0 = pack8(k0, k1), kf1 = pack8(k2, k3);
        f16x8 ef00 = pack8(ea0, ea1), ef01 = pack8(ea2, ea3);
        f16x8 ef10 = pack8(eb0, eb1), ef11 = pack8(eb2, eb3);

        const f32x4 z = {0.f, 0.f, 0.f, 0.f};
        f32x4 dk = MFMA(qa0, kf0, z);  dk = MFMA(qa1, kf1, dk);
        f32x4 g0 = MFMA(qa0, ef00, z); g0 = MFMA(qa1, ef01, g0);
        f32x4 g1 = MFMA(qa0, ef10, z); g1 = MFMA(qa1, ef11, g1);

        // sheared G gather via in-wave bpermute: G[rl][lj] lives in reg i of lane (o4, lj&15)
#pragma unroll
        for (int i = 0; i < 4; ++i) {
            const int rl  = 4 * o4 + i;
            const int lj  = lc + 15 - rl;            // in [0,30]
            const int src = (o4 << 4) | (lj & 15);
            float ga = __shfl(g0[i], src, 64);
            float gb = __shfl(g1[i], src, 64);
            float gv = (lj < 16) ? ga : gb;
            float s = (dk[i] + gv) * 0.125f;
            const int c = c0w + lc;
            if (c > r0 + rl) s = -60000.f;           // fp16-safe "-inf"
            mx[i] = fmaxf(mx[i], s);
            S_h[rl][swc(rl, c)] = (__fp16)s;
        }
    }

#pragma unroll
    for (int i = 0; i < 4; ++i)
        maxF[4 * o4 + i][(wave << 4) | lc] = mx[i];
    __syncthreads();

    // ================= pass 2+3: softmax + attn store (wave w owns rows 2w..2w+1) =========
    for (int rr = 0; rr < 2; ++rr) {
        const int rl = (wave << 1) + rr;
        const int r  = r0 + rl;
        float m = fmaxf(maxF[rl][lane], maxF[rl][64 + lane]);
#pragma unroll
        for (int off = 32; off; off >>= 1) m = fmaxf(m, __shfl_xor(m, off, 64));
        float l = 0.f;
        for (int t = 0; t < nT; ++t) {
            const int c  = (t << 6) + lane;
            const int cs = swc(rl, c);
            float p = (c <= r) ? __expf((float)S_h[rl][cs] - m) : 0.f;
            l += p;
            S_h[rl][cs] = (__fp16)p;                 // masked/garbage cols overwritten with 0
        }
#pragma unroll
        for (int off = 32; off; off >>= 1) l += __shfl_xor(l, off, 64);
        const float inv = 1.f / l;
        if (lane == 0) linv[rl] = inv;
        float* arow = out_attn + ((size_t)b * LL + r) * LL;
#pragma unroll 4
        for (int t = 0; t < LL / 64; ++t) {
            const int c = (t << 6) + lane;
            arow[c] = (c <= r) ? (float)S_h[rl][swc(rl, c)] * inv : 0.f;
        }
    }
    __syncthreads();   // all P in S_h; maxF free for reuse

    // ================= pass 4: O = P@V via MFMA; d-split x key-split ===============
    const int dw = (wave & 3) << 4;      // d-chunk base
    const int th = wave >> 2;            // key-tile parity
    f32x4 acc = {0.f, 0.f, 0.f, 0.f};
    const int koff = o4 << 3;

    for (int t = th; t < nT; t += 2) {
        const int cb = t << 6;
        // A-frags: P rows (row = lc), keys cb+kbase+8*o4+e  (one b128 each, swizzled)
        f16x8 pa0 = *(const f16x8*)&S_h[lc][swc(lc, cb + koff)];
        f16x8 pa1 = *(const f16x8*)&S_h[lc][swc(lc, cb + 32 + koff)];
        // B-frags: V[key][d], col = d = dw+lc, k = key
        const float* vp0 = vb + (size_t)(cb + koff) * DD + dw + lc;
        const float* vp1 = vb + (size_t)(cb + 32 + koff) * DD + dw + lc;
        float a0 = vp0[0],      a1 = vp0[DD],     a2 = vp0[2*DD], a3 = vp0[3*DD];
        float a4 = vp0[4*DD],   a5 = vp0[5*DD],   a6 = vp0[6*DD], a7 = vp0[7*DD];
        float c0 = vp1[0],      c1 = vp1[DD],     c2 = vp1[2*DD], c3 = vp1[3*DD];
        float c4 = vp1[4*DD],   c5 = vp1[5*DD],   c6 = vp1[6*DD], c7 = vp1[7*DD];
        f16x8 vf0 = pack8(make_float4(a0, a1, a2, a3), make_float4(a4, a5, a6, a7));
        f16x8 vf1 = pack8(make_float4(c0, c1, c2, c3), make_float4(c4, c5, c6, c7));
        acc = MFMA(pa0, vf0, acc);
        acc = MFMA(pa1, vf1, acc);
    }

    // cross-pair reduction (waves w and w+4 share d-chunk) via maxF scratch (4 KB)
    float* red = &maxF[0][0];
    if (wave >= 4) {
#pragma unroll
        for (int i = 0; i < 4; ++i)
            red[(wave & 3) * 256 + (4 * o4 + i) * 16 + lc] = acc[i];
    }
    __syncthreads();
    if (wave < 4) {
#pragma unroll
        for (int i = 0; i < 4; ++i) {
            const int rl = 4 * o4 + i;
            float oo = acc[i] + red[wave * 256 + rl * 16 + lc];
            out_o[((size_t)b * LL + r0 + rl) * DD + dw + lc] = oo * linv[rl];
        }
    }
}

extern "C" void kernel_launch(void* const* d_in, const int* in_sizes, int n_in,
                              void* d_out, int out_size, void* d_ws, size_t ws_size,
                              hipStream_t stream) {
    const float* q = (const float*)d_in[0];
    const float* k = (const float*)d_in[1];
    const float* v = (const float*)d_in[2];
    const float* e = (const float*)d_in[3];
    // d_in[4] = mask: causal, deterministic -> unused
    float* out_o    = (float*)d_out;
    float* out_attn = out_o + (size_t)BB * LL * DD;

    dim3 grid(BB * NBLK);
    attn_fused<<<grid, NTHREADS, 0, stream>>>(q, k, v, e, out_o, out_attn);
}